// Round 8
// baseline (64.297 us; speedup 1.0000x reference)
//
#include <hip/hip_runtime.h>

#define BLOCK 256
typedef float f32x4 __attribute__((ext_vector_type(4)));

// One thread per OUTPUT float4: j in [0, M*7), atom a=j/7, quad q=j%7.
// Zero LDS, zero fences. Stores perfectly coalesced per instruction
// (64 lanes x 16B contiguous). grid*BLOCK is a multiple of 7, so each
// thread's q is loop-invariant -> its 4 W-rows/bias hoist into registers.
// Input rows (28B) are read redundantly by the 7 threads of an atom —
// same-wave, L1-served; HBM sees each line once. Tables stay in L1 (3.1KB).
__global__ __launch_bounds__(BLOCK) void efp_kernel(
    const float* __restrict__ info,   // [M,7]
    const float* __restrict__ mask,   // [M]
    const float* __restrict__ W,      // [16,5]
    const float* __restrict__ bias,   // [16]
    const float* __restrict__ atom,   // [95,8]
    const float* __restrict__ typ,    // [6,4]
    float* __restrict__ out,          // [M,28] = [M*7] float4
    int nquads)                       // M*7
{
    const int j0 = blockIdx.x * BLOCK + threadIdx.x;
    const int stride = gridDim.x * BLOCK;   // multiple of 7 (grid=1792)
    const int q = j0 % 7;                   // loop-invariant per thread

    // hoist this thread's W rows / biases into registers (q<4 lanes only)
    float w[20], bb[4];
    if (q < 4) {
        #pragma unroll
        for (int o = 0; o < 4; ++o) {
            bb[o] = bias[q * 4 + o];
            #pragma unroll
            for (int k = 0; k < 5; ++k)
                w[o * 5 + k] = W[(q * 4 + o) * 5 + k];
        }
    }

    f32x4* out4 = reinterpret_cast<f32x4*>(out);

    for (int j = j0; j < nquads; j += stride) {
        const int a = j / 7;                 // magic-mul
        const float m = mask[a];             // {0,1}; ~10 lines/wave, coalesced
        const float* gi = info + (long long)a * 7;
        const bool active = (m >= 0.5f);
        f32x4 v;
        if (q < 4) {
            // exact reference semantics: mask-scale, linear, relu, mask gates
            const float f0 = gi[0] * m, f1 = gi[1] * m, f2 = gi[2] * m,
                        f3 = gi[3] * m, f4 = gi[4] * m;
            const float sc = active ? m : 0.0f;
            #pragma unroll
            for (int o = 0; o < 4; ++o) {
                float acc = bb[o];
                acc = fmaf(w[o * 5 + 0], f0, acc);
                acc = fmaf(w[o * 5 + 1], f1, acc);
                acc = fmaf(w[o * 5 + 2], f2, acc);
                acc = fmaf(w[o * 5 + 3], f3, acc);
                acc = fmaf(w[o * 5 + 4], f4, acc);
                v[o] = fmaxf(acc, 0.0f) * sc;
            }
        } else {
            const float r5 = gi[5];
            const int an = (int)(r5 * m);    // trunc toward zero (.astype int32)
            const bool valid = active && (an >= 1) && (an <= 94);
            const int anc = min(max(an, 0), 94);
            const float sc = valid ? m : 0.0f;
            const float* src;
            if (q == 6) {
                const float r6 = gi[6];
                const int etc = min(max((int)(r6 * m), 0), 5);
                src = typ + etc * 4;         // 16B aligned
            } else {
                src = atom + anc * 8 + (q - 4) * 4;  // 16B aligned half-row
            }
            const f32x4 t = *reinterpret_cast<const f32x4*>(src);
            v = t * sc;
        }
        __builtin_nontemporal_store(v, out4 + j);   // single-use stream
    }
}

extern "C" void kernel_launch(void* const* d_in, const int* in_sizes, int n_in,
                              void* d_out, int out_size, void* d_ws, size_t ws_size,
                              hipStream_t stream) {
    const float* info = (const float*)d_in[0];
    const float* mask = (const float*)d_in[1];
    const float* W    = (const float*)d_in[2];
    const float* bias = (const float*)d_in[3];
    const float* atom = (const float*)d_in[4];
    const float* typ  = (const float*)d_in[5];
    float* out = (float*)d_out;

    const int M = in_sizes[1];               // B*N = 2097152
    const int nquads = M * 7;                // 14680064 = 1792*256*32 exactly
    const int grid = 1792;                   // stride 458752 = 7*65536

    hipLaunchKernelGGL(efp_kernel, dim3(grid), dim3(BLOCK), 0, stream,
                       info, mask, W, bias, atom, typ, out, nquads);
}

// Round 9
// 50.179 us; speedup vs baseline: 1.2814x; 1.2814x over previous
//
#include <hip/hip_runtime.h>

#define BLOCK 256
typedef float f32x4 __attribute__((ext_vector_type(4)));

// One thread per atom, wave-private, 4-tile fully-unrolled async pipeline.
// Input staged via global_load_lds (no VGPR round-trip), double-buffered,
// counted s_waitcnt vmcnt(N) — never drained to 0 in steady state (T3/T4).
// Output: per-lane ds_write_b128 x7 (stride-7 slot spread), coop NT float4
// stores (1024B/instr contiguous). DS pipe in-order per wave; ordering via
// memory-clobber asm (pattern HW-validated R3-R7).
__global__ __launch_bounds__(BLOCK, 3) void efp_kernel(
    const float* __restrict__ info,   // [M,7]
    const float* __restrict__ mask,   // [M]
    const float* __restrict__ W,      // [16,5]  (uniform -> SGPR)
    const float* __restrict__ bias,   // [16]
    const float* __restrict__ atom,   // [95,8]
    const float* __restrict__ typ,    // [6,4]
    float* __restrict__ out,          // [M,28]
    int ntiles)
{
    __shared__ f32x4 s_atom[95 * 3];         // rows padded to 48B
    __shared__ f32x4 s_typ[6];
    __shared__ f32x4 s_ib[4][2][128];        // per-wave dbuf in-stage (2KB each)
    __shared__ float s_im[4][2][64];         // per-wave dbuf mask stage
    __shared__ f32x4 s_ob[4][448];           // per-wave out-stage (7KB)

    const int tid = threadIdx.x;
    const int wid = tid >> 6;
    const int lane = tid & 63;

    if (tid < 190) {
        const int a = tid >> 1, j = tid & 1;
        s_atom[a * 3 + j] = reinterpret_cast<const f32x4*>(atom)[tid];
    }
    if (tid < 6) s_typ[tid] = reinterpret_cast<const f32x4*>(typ)[tid];
    __syncthreads();                         // only block barrier

    f32x4* const ob = s_ob[wid];

    // ---- STAGE: issue 3 global_load_lds for tile t into buffer B ----
    auto STAGE = [&](int t, int B) {
        const long long abase = (long long)t * BLOCK + wid * 64;
        const f32x4* g = reinterpret_cast<const f32x4*>(info + abase * 7) + lane;
        __builtin_amdgcn_global_load_lds(
            reinterpret_cast<const unsigned int*>(g),
            reinterpret_cast<unsigned int*>(&s_ib[wid][B][0]), 16, 0, 0);
        const f32x4* g2 = (64 + lane < 112) ? (g + 64) : (g - lane); // clamp: in-bounds, slot unread
        __builtin_amdgcn_global_load_lds(
            reinterpret_cast<const unsigned int*>(g2),
            reinterpret_cast<unsigned int*>(&s_ib[wid][B][64]), 16, 0, 0);
        __builtin_amdgcn_global_load_lds(
            reinterpret_cast<const unsigned int*>(mask + abase + lane),
            reinterpret_cast<unsigned int*>(&s_im[wid][B][0]), 4, 0, 0);
    };

    // ---- PROCESS: consume buffer B (after its vmcnt wait), store tile t ----
    auto PROCESS = [&](int t, int B) {
        const long long abase = (long long)t * BLOCK + wid * 64;
        const float* swf = reinterpret_cast<const float*>(&s_ib[wid][B][0]);
        const float m = s_im[wid][B][lane];
        float r[7];
        #pragma unroll
        for (int k = 0; k < 7; ++k) r[k] = swf[lane * 7 + k];  // 7 coprime 32

        // exact reference semantics
        const float f0 = r[0] * m, f1 = r[1] * m, f2 = r[2] * m,
                    f3 = r[3] * m, f4 = r[4] * m;
        const int an = (int)(r[5] * m);        // trunc toward zero
        const int et = (int)(r[6] * m);
        const bool active = (m >= 0.5f);
        const bool valid  = active && (an >= 1) && (an <= 94);
        const int anc = min(max(an, 0), 94);
        const int etc = min(max(et, 0), 5);
        const float sc_ff  = active ? m : 0.0f;
        const float sc_emb = valid  ? m : 0.0f;

        f32x4 o[7];
        float* of = reinterpret_cast<float*>(o);
        #pragma unroll
        for (int oo = 0; oo < 16; ++oo) {
            float acc = bias[oo];
            acc = fmaf(W[oo * 5 + 0], f0, acc);
            acc = fmaf(W[oo * 5 + 1], f1, acc);
            acc = fmaf(W[oo * 5 + 2], f2, acc);
            acc = fmaf(W[oo * 5 + 3], f3, acc);
            acc = fmaf(W[oo * 5 + 4], f4, acc);
            of[oo] = fmaxf(acc, 0.0f) * sc_ff;
        }
        const f32x4 a0 = s_atom[anc * 3 + 0];
        const f32x4 a1 = s_atom[anc * 3 + 1];
        const f32x4 t0 = s_typ[etc];
        o[4] = a0 * sc_emb;
        o[5] = a1 * sc_emb;
        o[6] = t0 * sc_emb;

        #pragma unroll
        for (int q = 0; q < 7; ++q) ob[lane * 7 + q] = o[q];   // mod-8 spread

        asm volatile("s_waitcnt lgkmcnt(0)" ::: "memory");     // out-stage + input reads done

        f32x4* go = reinterpret_cast<f32x4*>(out) + abase * 7;
        #pragma unroll
        for (int k = 0; k < 7; ++k) {
            const int l = k * 64 + lane;
            __builtin_nontemporal_store(ob[l], go + l);        // 7168B/wave burst
        }
        asm volatile("" ::: "memory");
    };

    const int S = gridDim.x;
    const int t0 = blockIdx.x;

    if (ntiles == S * 4) {                   // bench path: exactly 4 tiles/block
        const int t1 = t0 + S, t2 = t0 + 2 * S, t3 = t0 + 3 * S;
        STAGE(t0, 0);
        STAGE(t1, 1);
        asm volatile("s_waitcnt vmcnt(3)" ::: "memory");   // t0 landed (3 newer)
        PROCESS(t0, 0);                                    // +7 stores
        STAGE(t2, 0);
        asm volatile("s_waitcnt vmcnt(10)" ::: "memory");  // t1 landed (7 st + 3 ld newer)
        PROCESS(t1, 1);
        STAGE(t3, 1);
        asm volatile("s_waitcnt vmcnt(10)" ::: "memory");  // t2 landed
        PROCESS(t2, 0);
        asm volatile("s_waitcnt vmcnt(7)" ::: "memory");   // t3 landed (7 st newer)
        PROCESS(t3, 1);
    } else {                                 // generic fallback (correctness)
        for (int t = t0; t < ntiles; t += S) {
            STAGE(t, 0);
            asm volatile("s_waitcnt vmcnt(0)" ::: "memory");
            PROCESS(t, 0);
        }
    }
}

extern "C" void kernel_launch(void* const* d_in, const int* in_sizes, int n_in,
                              void* d_out, int out_size, void* d_ws, size_t ws_size,
                              hipStream_t stream) {
    const float* info = (const float*)d_in[0];
    const float* mask = (const float*)d_in[1];
    const float* W    = (const float*)d_in[2];
    const float* bias = (const float*)d_in[3];
    const float* atom = (const float*)d_in[4];
    const float* typ  = (const float*)d_in[5];
    float* out = (float*)d_out;

    const int M = in_sizes[1];               // B*N = 2097152
    const int ntiles = M / BLOCK;            // 8192
    int grid = ntiles < 2048 ? ntiles : 2048;

    hipLaunchKernelGGL(efp_kernel, dim3(grid), dim3(BLOCK), 0, stream,
                       info, mask, W, bias, atom, typ, out, ntiles);
}